// Round 13
// baseline (735.397 us; speedup 1.0000x reference)
//
#include <hip/hip_runtime.h>
#include <stdint.h>

typedef __attribute__((ext_vector_type(8))) short bf16x8;
typedef __attribute__((ext_vector_type(4))) float f32x4;
typedef __attribute__((ext_vector_type(4))) unsigned int u32x4;

#define DEV __device__ __forceinline__

DEV float bf2f(unsigned short u){ union{unsigned int i; float f;} v; v.i=((unsigned int)u)<<16; return v.f; }
DEV unsigned short f2bf(float f){ union{float f; unsigned int i;} v; v.f=f; unsigned int x=v.i;
  return (unsigned short)((x + 0x7fffu + ((x>>16)&1u)) >> 16); }

// ---------------------------------------------------------------------------
// Fused s=1 prep: theta = (W_t x + b_t)*10*log2(e)  [bf16 CL padded 134x136x16]
//                 phi0  = W_p x + b_p               [bf16 CL padded]
//                 g0    = W_g x + b_g               [f32 CF padded 16x134x136]
// ---------------------------------------------------------------------------
__global__ void k_prep1(const float* __restrict__ x,
                        const float* __restrict__ wt, const float* __restrict__ bt,
                        const float* __restrict__ wp, const float* __restrict__ bp,
                        const float* __restrict__ wg, const float* __restrict__ bg,
                        unsigned short* __restrict__ th, unsigned short* __restrict__ ph,
                        float* __restrict__ gt)
{
  __shared__ float red[3][64][48];
  int tid = threadIdx.x;
  int grp = tid >> 6, pixl = tid & 63;
  int pix = blockIdx.x*64 + pixl;          // [0, 32768)
  int b = pix >> 14, p = pix & 16383, i = p >> 7, j = p & 127;
  float a[48];
#pragma unroll
  for (int c=0;c<48;++c) a[c]=0.f;
  const float* xb = x + (size_t)b*64*16384 + p;
#pragma unroll
  for (int c4=0; c4<4; ++c4) {
    int cc = grp*16 + c4*4;
    float xv[4];
#pragma unroll
    for (int u=0;u<4;++u) xv[u] = xb[(size_t)(cc+u)*16384];
#pragma unroll
    for (int ic=0;ic<16;++ic) {
      float4 w0 = *(const float4*)(wt + ic*64 + cc);
      float4 w1 = *(const float4*)(wp + ic*64 + cc);
      float4 w2 = *(const float4*)(wg + ic*64 + cc);
      a[ic]    += xv[0]*w0.x + xv[1]*w0.y + xv[2]*w0.z + xv[3]*w0.w;
      a[16+ic] += xv[0]*w1.x + xv[1]*w1.y + xv[2]*w1.z + xv[3]*w1.w;
      a[32+ic] += xv[0]*w2.x + xv[1]*w2.y + xv[2]*w2.z + xv[3]*w2.w;
    }
  }
  if (grp) {
#pragma unroll
    for (int c=0;c<48;++c) red[grp-1][pixl][c] = a[c];
  }
  __syncthreads();
  if (grp == 0) {
#pragma unroll
    for (int c=0;c<48;++c) a[c] += red[0][pixl][c] + red[1][pixl][c] + red[2][pixl][c];
    const float TEMPC = 14.426950408889634f;
    unsigned short o[16];
#pragma unroll
    for (int ic=0;ic<16;++ic) o[ic] = f2bf((a[ic]+bt[ic])*TEMPC);
    uint4* d0 = (uint4*)(th + ((size_t)(b*134 + i+3)*136 + (j+3))*16);
    d0[0]=*(uint4*)&o[0]; d0[1]=*(uint4*)&o[8];
#pragma unroll
    for (int ic=0;ic<16;++ic) o[ic] = f2bf(a[16+ic]+bp[ic]);
    uint4* d1 = (uint4*)(ph + ((size_t)(b*134 + i+3)*136 + (j+3))*16);
    d1[0]=*(uint4*)&o[0]; d1[1]=*(uint4*)&o[8];
#pragma unroll
    for (int ic=0;ic<16;++ic)
      gt[(((size_t)b*16+ic)*134 + i+3)*136 + (j+3)] = a[32+ic]+bg[ic];
  }
}

// ---------------------------------------------------------------------------
// s=2 conv: phi1 (bf16 CL padded 70x72x16), g1 (f32 CF padded 16x70x72)
// ---------------------------------------------------------------------------
__global__ void k_conv2(const float* __restrict__ x,
                        const float* __restrict__ wp, const float* __restrict__ bp,
                        const float* __restrict__ wg, const float* __restrict__ bg,
                        unsigned short* __restrict__ phi, float* __restrict__ gt)
{
  __shared__ float red[3][64][32];
  int tid = threadIdx.x;
  int grp = tid >> 6, pixl = tid & 63;
  int pix = blockIdx.x*64 + pixl;          // [0, 8192)
  int b = pix >> 12, p = pix & 4095, i = p >> 6, j = p & 63;
  float a[32];
#pragma unroll
  for (int c=0;c<32;++c) a[c]=0.f;
  const float* xb = x + (size_t)b*64*16384 + (i*2)*128 + j*2;
#pragma unroll
  for (int c0=0; c0<16; ++c0) {
    int cc = grp*16 + c0;
    const float* xp = xb + (size_t)cc*16384;
    float xv[4];
    xv[0]=xp[0]; xv[1]=xp[1]; xv[2]=xp[128]; xv[3]=xp[129];
#pragma unroll
    for (int ic=0;ic<16;++ic) {
      float4 w0 = *(const float4*)(wp + (ic*64+cc)*4);
      float4 w1 = *(const float4*)(wg + (ic*64+cc)*4);
      a[ic]    += xv[0]*w0.x + xv[1]*w0.y + xv[2]*w0.z + xv[3]*w0.w;
      a[16+ic] += xv[0]*w1.x + xv[1]*w1.y + xv[2]*w1.z + xv[3]*w1.w;
    }
  }
  if (grp) {
#pragma unroll
    for (int c=0;c<32;++c) red[grp-1][pixl][c] = a[c];
  }
  __syncthreads();
  if (grp == 0) {
#pragma unroll
    for (int c=0;c<32;++c) a[c] += red[0][pixl][c] + red[1][pixl][c] + red[2][pixl][c];
    unsigned short o[16];
#pragma unroll
    for (int ic=0;ic<16;++ic) o[ic] = f2bf(a[ic]+bp[ic]);
    uint4* d1 = (uint4*)(phi + ((size_t)(b*70 + i+3)*72 + (j+3))*16);
    d1[0]=*(uint4*)&o[0]; d1[1]=*(uint4*)&o[8];
#pragma unroll
    for (int ic=0;ic<16;++ic)
      gt[(((size_t)b*16+ic)*70 + i+3)*72 + (j+3)] = a[16+ic]+bg[ic];
  }
}

// ---------------------------------------------------------------------------
// Transpose s=4 weights: wT[k][32], k = cc*16 + a*4 + bb; c<16 phi, else g
// ---------------------------------------------------------------------------
__global__ void k_wt4(const float* __restrict__ wp, const float* __restrict__ wg,
                      float* __restrict__ wT)
{
  int idx = blockIdx.x*256 + threadIdx.x;
  if (idx >= 1024*32) return;
  int k = idx >> 5, c = idx & 31;
  int cc = k >> 4, ksp = k & 15;
  float v = (c < 16) ? wp[(c*64+cc)*16 + ksp] : wg[((c-16)*64+cc)*16 + ksp];
  wT[idx] = v;
}

// ---------------------------------------------------------------------------
// s=4 conv: 8 pixels x 32 out-channels; x patches staged in LDS
// ---------------------------------------------------------------------------
__global__ void k_conv4(const float* __restrict__ x, const float* __restrict__ wT,
                        const float* __restrict__ bp, const float* __restrict__ bg,
                        unsigned short* __restrict__ phi, float* __restrict__ gt)
{
  __shared__ float xs[8][1028];
  int tid = threadIdx.x;
  int pix0 = blockIdx.x*8;                 // [0,2048) step 8
  for (int idx = tid; idx < 8*1024; idx += 256) {
    int pl = idx >> 10, e = idx & 1023;
    int pix = pix0 + pl; int b = pix >> 10, p = pix & 1023, i = p >> 5, j = p & 31;
    int cc = e >> 4, a_ = (e >> 2) & 3, bb = e & 3;
    xs[pl][e] = x[(((size_t)b*64+cc)*128 + i*4+a_)*128 + j*4+bb];
  }
  __syncthreads();
  int pp = tid >> 5, icp = tid & 31;
  int pix = pix0 + pp; int b = pix >> 10, p = pix & 1023, i = p >> 5, j = p & 31;
  float acc = 0.f;
#pragma unroll 8
  for (int k4=0; k4<256; ++k4) {
    float4 xv = *(const float4*)(&xs[pp][k4*4]);
    acc += xv.x*wT[(k4*4  )*32+icp] + xv.y*wT[(k4*4+1)*32+icp]
         + xv.z*wT[(k4*4+2)*32+icp] + xv.w*wT[(k4*4+3)*32+icp];
  }
  int ic = icp & 15;
  if (icp < 16)
    phi[(((size_t)(b*38 + i+3)*40) + (j+3))*16 + ic] = f2bf(acc + bp[ic]);
  else
    gt[(((size_t)b*16+ic)*38 + i+3)*40 + (j+3)] = acc + bg[ic];
}

// ---------------------------------------------------------------------------
// V tile buffer: g8b[b][sh][y][xb][c][32] bf16 (1KB tile per (sh,y,xb)).
// ---------------------------------------------------------------------------
template<int HP, int WX, int HS>
__global__ void k_shiftB(const float* __restrict__ gt, unsigned short* __restrict__ g8b)
{
  const int XB = HS/32;
  int idx = blockIdx.x*256 + threadIdx.x;
  const int TOT = 2*8*HP*XB*16*4;
  if (idx >= TOT) return;
  int xkg = idx & 3;
  int c = (idx >> 2) & 15;
  int t = idx >> 6;
  int xb = t % XB; t /= XB;
  int y = t % HP; t /= HP;
  int sh = t & 7; int b = t >> 3;
  const float* src = gt + (((size_t)b*16+c)*HP + y)*WX + xb*32 + xkg*8 + sh;
  unsigned short o[8];
#pragma unroll
  for (int j=0;j<8;++j) o[j] = f2bf(src[j]);
  unsigned short* dst = g8b + ((((size_t)(b*8+sh)*HP + y)*XB + xb)*16 + c)*32 + xkg*8;
  *(uint4*)dst = *(uint4*)&o[0];
}

// ---------------------------------------------------------------------------
// Flash attention, fixed shift P = exp2(min(sc-64,120)). Q-tile 32, 8 waves,
// 256 keys/iter. PHI window staged per-iter into LDS via async
// global_load_lds (issued after B1, overlapped with PV, drained by B2's
// implicit vmcnt(0)). theta from global (iter-invariant -> L1-hot; V is
// nontemporal so L1 holds only theta). accP stores nontemporal.
// ---------------------------------------------------------------------------
template<int HS, int LG, int HP, int WX, int CK, int NCH>
__global__ void __launch_bounds__(512, 2)
k_attn(const unsigned short* __restrict__ th, const unsigned short* __restrict__ phi,
       const unsigned short* __restrict__ g8b, float* __restrict__ accP,
       float* __restrict__ lP)
{
  // LDS: phi window (<=40960 B) | P 32q x 256k bf16 = 16384 B
  __shared__ __align__(16) char smem[40960 + 16384];
  const int PO = 40960;

  int tid = threadIdx.x;
  int w = tid >> 6, lane = tid & 63, l15 = lane & 15, g = lane >> 4;
  int bid = blockIdx.x;
  int chunk, b, qt;
  if (NCH == 8) { chunk = bid & 7; b = (bid >> 3) & 1; qt = bid >> 4; }
  else          { chunk = bid & 3; b = (bid >> 2) & 1; qt = bid >> 3; }
  int q0 = qt * 32;

  const char* thB  = (const char*)th  + (size_t)b*134*136*32;
  const char* phiB = (const char*)phi + (size_t)b*HP*WX*32;

  constexpr int ROWS = (256 >> LG) + 6;        // phi rows per 256-key window
  constexpr int BYTES = ROWS*WX*32;
  constexpr int NST = (BYTES + 8191)/8192;     // 8KB per staging call (512 thr x 16B)

  // ---- stage phi window for iter 0 ----
  {
    int krn = (chunk*CK) >> LG;
    const char* srcb = phiB + (size_t)krn*WX*32 + tid*16;
    char* dstb = smem + (tid>>6)*1024;
#pragma unroll
    for (int u=0; u<NST; ++u)
      __builtin_amdgcn_global_load_lds(
        (const __attribute__((address_space(1))) unsigned int*)(srcb + u*8192),
        (__attribute__((address_space(3))) unsigned int*)(dstb + u*8192), 16, 0, 0);
  }
  __syncthreads();                             // drains vmcnt -> phi ready

  f32x4 acc[2][7];
#pragma unroll
  for (int rt=0;rt<2;++rt)
#pragma unroll
    for (int et=0;et<7;++et) acc[rt][et] = f32x4{0.f,0.f,0.f,0.f};
  float lacc[2][4];
#pragma unroll
  for (int rt=0;rt<2;++rt)
#pragma unroll
    for (int r=0;r<4;++r) lacc[rt][r] = 0.f;

  const int XBv = HS/32;
  const char* g8B  = (const char*)g8b + (size_t)b*8*HP*XBv*1024;
  const int EPL = HP*XBv*1024;                 // bytes per shift-plane
  int laneVb = l15*64 + g*16;                  // within 1KB tile
  int xrP = (l15 & 7) << 4;                    // P-lds read swizzle
  int hb = (g & 1) << 4;
  int tb = ((4*qt+2)*136 + 4*l15 + 2)*32 + hb; // theta global base (Q-tile 32)
  const bf16x8 ZV = {0,0,0,0,0,0,0,0};
  const int ITERS = CK/256;
  const float SHIFT = 64.0f, CLAMP = 120.0f;

#pragma unroll 1
  for (int it = 0; it < ITERS; ++it) {
    int k0 = chunk*CK + it*256;
    int kr0 = k0 >> LG;
    asm volatile("" : "+v"(tb));
    // ---------------- QK ----------------
    f32x4 sc[2][2];
#pragma unroll
    for (int rt=0;rt<2;++rt){ sc[rt][0]=f32x4{0.f,0.f,0.f,0.f}; sc[rt][1]=f32x4{0.f,0.f,0.f,0.f}; }
    int kr_w = (k0 + w*32) >> LG;
    int lrw = kr_w - kr0;
    int kc_w = (w*32) & (HS-1);
    int base0 = (lrw*WX + kc_w + l15)*32 + hb;   // phi LDS base (linear)
#pragma unroll
    for (int ks=0; ks<25; ++ks) {
      int p0 = 2*ks;
      int p1 = (2*ks+1 > 48) ? 48 : 2*ks+1;
      int KA0 = ((p0/7)*136 + (p0%7))*32;
      int KA1 = ((p1/7)*136 + (p1%7))*32;
      int KB0 = ((p0/7)*WX  + (p0%7))*32;
      int KB1 = ((p1/7)*WX  + (p1%7))*32;
      int selA = (g & 2) ? KA1 : KA0;
      int selB = (g & 2) ? KB1 : KB0;
      bf16x8 a0 = *(const bf16x8*)(thB + tb + selA);
      bf16x8 a1 = *(const bf16x8*)(thB + tb + selA + 2048);
      if (ks == 24) {
        bool z = (g & 2) != 0;
        a0 = z ? ZV : a0; a1 = z ? ZV : a1;
      }
      bf16x8 b0 = *(const bf16x8*)(smem + base0 + selB);
      bf16x8 b1 = *(const bf16x8*)(smem + base0 + selB + 512);
      sc[0][0] = __builtin_amdgcn_mfma_f32_16x16x32_bf16(a0, b0, sc[0][0], 0,0,0);
      sc[0][1] = __builtin_amdgcn_mfma_f32_16x16x32_bf16(a0, b1, sc[0][1], 0,0,0);
      sc[1][0] = __builtin_amdgcn_mfma_f32_16x16x32_bf16(a1, b0, sc[1][0], 0,0,0);
      sc[1][1] = __builtin_amdgcn_mfma_f32_16x16x32_bf16(a1, b1, sc[1][1], 0,0,0);
    }
    // ---------------- P = exp2(min(S-64,120)), accumulate l, write P_lds ----------------
#pragma unroll
    for (int rt=0;rt<2;++rt) {
#pragma unroll
      for (int r=0;r<4;++r) {
        float pa = __builtin_amdgcn_exp2f(fminf(sc[rt][0][r] - SHIFT, CLAMP));
        float pb = __builtin_amdgcn_exp2f(fminf(sc[rt][1][r] - SHIFT, CLAMP));
        lacc[rt][r] += pa + pb;
        int q_ = rt*16 + g*4 + r;
        int offa = q_*512 + (w*32 + l15)*2;      offa ^= (q_&7)<<4;
        int offb = q_*512 + (w*32 + 16 + l15)*2; offb ^= (q_&7)<<4;
        *(unsigned short*)(smem + PO + offa) = f2bf(pa);
        *(unsigned short*)(smem + PO + offb) = f2bf(pb);
      }
    }
    __syncthreads();                 // B1: P ready, all QK phi reads done
    // ---- issue async stage of next phi window (overlaps with PV) ----
    if (it+1 < ITERS) {
      int krn = (chunk*CK + (it+1)*256) >> LG;
      const char* srcb = phiB + (size_t)krn*WX*32 + tid*16;
      char* dstb = smem + (tid>>6)*1024;
#pragma unroll
      for (int u=0; u<NST; ++u)
        __builtin_amdgcn_global_load_lds(
          (const __attribute__((address_space(1))) unsigned int*)(srcb + u*8192),
          (__attribute__((address_space(3))) unsigned int*)(dstb + u*8192), 16, 0, 0);
    }
    // ---------------- PV ----------------
    if (w < 7) {
#pragma unroll
      for (int ks2=0; ks2<8; ++ks2) {
        int kk = k0 + ks2*32;
        int krv = kk >> LG;
        int kcb = kk & (HS-1);
        bf16x8 pf[2];
#pragma unroll
        for (int rt=0;rt<2;++rt) {
          int off = (rt*16 + l15)*512 + ks2*64 + g*16;
          off ^= xrP;
          pf[rt] = *(const bf16x8*)(smem + PO + off);
        }
        int vb = ((krv + w)*XBv + (kcb >> 5))*1024 + laneVb;
        bf16x8 vf[7];
#pragma unroll
        for (int et=0;et<7;++et) {
          u32x4 t0 = __builtin_nontemporal_load((const u32x4*)(g8B + vb + et*EPL));
          vf[et] = *(bf16x8*)&t0;
        }
#pragma unroll
        for (int rt=0;rt<2;++rt)
#pragma unroll
          for (int et=0;et<7;++et)
            acc[rt][et] = __builtin_amdgcn_mfma_f32_16x16x32_bf16(pf[rt], vf[et], acc[rt][et], 0,0,0);
      }
    }
    __syncthreads();                 // B2: stage complete (vmcnt drain) + P protected
  }
  if (w < 7) {
    float* accB = accP + ((size_t)(chunk*2 + b)*1024)*784;
#pragma unroll
    for (int rt=0;rt<2;++rt)
#pragma unroll
      for (int et=0;et<7;++et)
#pragma unroll
        for (int r=0;r<4;++r)
          __builtin_nontemporal_store(acc[rt][et][r],
            &accB[(size_t)(q0 + rt*16 + g*4 + r)*784 + (w*7+et)*16 + l15]);
  }
  // per-wave l partials: reduce over the 16-lane group, write one slot per wave
#pragma unroll
  for (int st=1; st<16; st<<=1)
#pragma unroll
    for (int rt=0;rt<2;++rt)
#pragma unroll
      for (int r=0;r<4;++r) lacc[rt][r] += __shfl_xor(lacc[rt][r], st);
  if (l15 == 0) {
#pragma unroll
    for (int rt=0;rt<2;++rt)
#pragma unroll
      for (int r=0;r<4;++r)
        lP[((size_t)((chunk*2 + b)*8 + w) << 10) + q0 + rt*16 + g*4 + r] = lacc[rt][r];
  }
}

// ---------------------------------------------------------------------------
// lG[b*1024+q] = sum over chunks and waves of lP
// ---------------------------------------------------------------------------
__global__ void k_comb1(const float* __restrict__ lP, float* __restrict__ lG, int nch)
{
  int idx = blockIdx.x*256 + threadIdx.x;
  if (idx >= 2048) return;
  int b = idx >> 10, q = idx & 1023;
  float l = 0.f;
  for (int c=0;c<nch;++c)
#pragma unroll
    for (int w=0;w<8;++w)
      l += lP[((size_t)((c*2 + b)*8 + w) << 10) + q];
  lG[idx] = l;
}

// ---------------------------------------------------------------------------
// Sum partial accs over chunks (directly summable, shared shift), / lG
// ---------------------------------------------------------------------------
__global__ void k_comb2(const float* __restrict__ accP, const float* __restrict__ lG,
                        float* __restrict__ yvf, int nch)
{
  int idx = blockIdx.x*256 + threadIdx.x;
  if (idx >= 2048*196) return;
  int bq = idx / 196, f4 = idx % 196;
  float4 s = {0.f,0.f,0.f,0.f};
  for (int c=0;c<nch;++c) {
    float4 v = *(const float4*)(accP + ((size_t)(c*2048 + bq))*784 + f4*4);
    s.x += v.x; s.y += v.y; s.z += v.z; s.w += v.w;
  }
  float inv = 1.0f / lG[bq];
  s.x*=inv; s.y*=inv; s.z*=inv; s.w*=inv;
  *(float4*)(yvf + (size_t)bq*784 + f4*4) = s;
}

// ---------------------------------------------------------------------------
// fold (stride-4, pad 3) + /mask -> y_cl[b][i][j][48]
// ---------------------------------------------------------------------------
template<int SC>
__global__ void k_fold_f32(const float* __restrict__ yvf, float* __restrict__ ycl)
{
  int idx = blockIdx.x*256 + threadIdx.x;
  if (idx >= 2*128*128) return;
  int j = idx & 127; int t = idx >> 7; int i = t & 127; int b = t >> 7;
  float a[16];
#pragma unroll
  for (int c=0;c<16;++c) a[c]=0.f;
  const float* yb = yvf + (size_t)b*1024*784;

  int drs[2], qis[2], cnti=0;
  int dcs[2], qjs[2], cntj=0;
#pragma unroll
  for (int dr=0; dr<7; ++dr) {
    int tr = i + 3 - dr;
    if (tr >= 0 && (tr & 3) == 0 && (tr >> 2) < 32) { drs[cnti]=dr; qis[cnti]=tr>>2; ++cnti; }
  }
#pragma unroll
  for (int dc=0; dc<7; ++dc) {
    int tc = j + 3 - dc;
    if (tc >= 0 && (tc & 3) == 0 && (tc >> 2) < 32) { dcs[cntj]=dc; qjs[cntj]=tc>>2; ++cntj; }
  }
  for (int u=0; u<cnti; ++u) {
    for (int v=0; v<cntj; ++v) {
      const float* src = yb + (size_t)(qis[u]*32 + qjs[v])*784 + (drs[u]*7 + dcs[v])*16;
      float4 v0 = *(const float4*)(src);
      float4 v1 = *(const float4*)(src+4);
      float4 v2 = *(const float4*)(src+8);
      float4 v3 = *(const float4*)(src+12);
      a[0]+=v0.x; a[1]+=v0.y; a[2]+=v0.z; a[3]+=v0.w;
      a[4]+=v1.x; a[5]+=v1.y; a[6]+=v1.z; a[7]+=v1.w;
      a[8]+=v2.x; a[9]+=v2.y; a[10]+=v2.z; a[11]+=v2.w;
      a[12]+=v3.x; a[13]+=v3.y; a[14]+=v3.z; a[15]+=v3.w;
    }
  }
  float inv = 1.0f / (float)(cnti*cntj);
  float* dst = ycl + (size_t)idx*48 + SC*16;
#pragma unroll
  for (int c=0;c<16;++c) dst[c] = a[c]*inv;
}

// ---------------------------------------------------------------------------
// out = conv1x1(y, w_out) + b_out + x
// ---------------------------------------------------------------------------
__global__ void k_final(const float* __restrict__ ycl, const float* __restrict__ wo,
                        const float* __restrict__ bo, const float* __restrict__ x,
                        float* __restrict__ out)
{
  __shared__ float wl[64*48];
  for (int t = threadIdx.x; t < 64*48; t += 256) wl[t] = wo[t];
  __syncthreads();
  int idx = blockIdx.x*256 + threadIdx.x;
  if (idx >= 2*128*128) return;
  int j = idx & 127; int t = idx >> 7; int i = t & 127; int b = t >> 7;
  float y[48];
  const float* ys = ycl + (size_t)idx*48;
#pragma unroll
  for (int c=0;c<48;++c) y[c] = ys[c];
  const float* xb = x + (size_t)b*64*16384 + i*128 + j;
  float* ob = out + (size_t)b*64*16384 + i*128 + j;
  for (int o=0;o<64;++o) {
    float s = bo[o];
#pragma unroll
    for (int c=0;c<48;++c) s += y[c]*wl[o*48+c];
    ob[(size_t)o*16384] = s + xb[(size_t)o*16384];
  }
}

// ---------------------------------------------------------------------------
extern "C" void kernel_launch(void* const* d_in, const int* in_sizes, int n_in,
                              void* d_out, int out_size, void* d_ws, size_t ws_size,
                              hipStream_t stream)
{
  const float* x  = (const float*)d_in[0];
  const float* wt = (const float*)d_in[1];
  const float* bt = (const float*)d_in[2];
  const float* wp0= (const float*)d_in[3];
  const float* bp0= (const float*)d_in[4];
  const float* wg0= (const float*)d_in[5];
  const float* bg0= (const float*)d_in[6];
  const float* wp1= (const float*)d_in[7];
  const float* bp1= (const float*)d_in[8];
  const float* wg1= (const float*)d_in[9];
  const float* bg1= (const float*)d_in[10];
  const float* wp2= (const float*)d_in[11];
  const float* bp2= (const float*)d_in[12];
  const float* wg2= (const float*)d_in[13];
  const float* bg2= (const float*)d_in[14];
  const float* wo = (const float*)d_in[15];
  const float* bo = (const float*)d_in[16];
  float* out = (float*)d_out;

  char* ws = (char*)d_ws;
  size_t off = 0;
  auto alloc = [&](size_t bytes)->char* { char* p = ws + off; off += (bytes + 255) & ~(size_t)255; return p; };
  unsigned short* th  = (unsigned short*)alloc(2ull*134*136*16*2);
  unsigned short* ph0 = (unsigned short*)alloc(2ull*134*136*16*2);
  unsigned short* ph1 = (unsigned short*)alloc(2ull*70*72*16*2);
  unsigned short* ph2 = (unsigned short*)alloc(2ull*38*40*16*2);
  float* gt0 = (float*)alloc(2ull*16*134*136*4);
  float* gt1 = (float*)alloc(2ull*16*70*72*4);
  float* gt2 = (float*)alloc(2ull*16*38*40*4);
  size_t zeroBytes = off;                      // th..gt2 contiguous prefix
  unsigned short* g80 = (unsigned short*)alloc(2ull*8*134*4*512*2);
  unsigned short* g81 = (unsigned short*)alloc(2ull*8*70*2*512*2);
  unsigned short* g82 = (unsigned short*)alloc(2ull*8*38*1*512*2);
  float* wT4 = (float*)alloc(1024ull*32*4);
  float* lP  = (float*)alloc(8ull*2*8*1024*4);
  float* lG  = (float*)alloc(2048*4);
  float* accP= (float*)alloc(8ull*2048*784*4);
  float* yvf = (float*)alloc(2048ull*784*4);
  float* ycl = (float*)alloc(2ull*128*128*48*4);
  (void)ws_size; (void)in_sizes; (void)n_in; (void)out_size;

  (void)hipMemsetAsync(ws, 0, zeroBytes, stream);  // zero padded borders of th/ph/gt

  k_prep1<<<512,256,0,stream>>>(x, wt,bt, wp0,bp0, wg0,bg0, th, ph0, gt0);
  k_conv2<<<128,256,0,stream>>>(x, wp1,bp1, wg1,bg1, ph1, gt1);
  k_wt4<<<128,256,0,stream>>>(wp2, wg2, wT4);
  k_conv4<<<256,256,0,stream>>>(x, wT4, bp2, bg2, ph2, gt2);
  k_shiftB<134,136,128><<<(2*8*134*4*16*4+255)/256,256,0,stream>>>(gt0, g80);
  k_shiftB<70,72,64>   <<<(2*8*70*2*16*4 +255)/256,256,0,stream>>>(gt1, g81);
  k_shiftB<38,40,32>   <<<(2*8*38*1*16*4 +255)/256,256,0,stream>>>(gt2, g82);

  const int CB2 = (2048*196 + 255)/256;
  // ---- scale 0 (s=1): 16384 keys, 8 chunks of 2048 (4 iters), 512 blocks ----
  k_attn<128,7,134,136,2048,8><<<512,512,0,stream>>>(th, ph0, g80, accP, lP);
  k_comb1<<<8,256,0,stream>>>(lP, lG, 8);
  k_comb2<<<CB2,256,0,stream>>>(accP, lG, yvf, 8);
  k_fold_f32<0><<<128,256,0,stream>>>(yvf, ycl);
  // ---- scale 1 (s=2): 4096 keys, 8 chunks of 512 (2 iters), 512 blocks ----
  k_attn<64,6,70,72,512,8><<<512,512,0,stream>>>(th, ph1, g81, accP, lP);
  k_comb1<<<8,256,0,stream>>>(lP, lG, 8);
  k_comb2<<<CB2,256,0,stream>>>(accP, lG, yvf, 8);
  k_fold_f32<1><<<128,256,0,stream>>>(yvf, ycl);
  // ---- scale 2 (s=4): 1024 keys, 4 chunks of 256 (1 iter), 256 blocks ----
  k_attn<32,5,38,40,256,4><<<256,512,0,stream>>>(th, ph2, g82, accP, lP);
  k_comb1<<<8,256,0,stream>>>(lP, lG, 4);
  k_comb2<<<CB2,256,0,stream>>>(accP, lG, yvf, 4);
  k_fold_f32<2><<<128,256,0,stream>>>(yvf, ycl);

  k_final<<<128,256,0,stream>>>(ycl, wo, bo, x, out);
}

// Round 14
// 558.404 us; speedup vs baseline: 1.3170x; 1.3170x over previous
//
#include <hip/hip_runtime.h>
#include <stdint.h>

typedef __attribute__((ext_vector_type(8))) short bf16x8;
typedef __attribute__((ext_vector_type(4))) float f32x4;
typedef __attribute__((ext_vector_type(4))) unsigned int u32x4;

#define DEV __device__ __forceinline__

DEV float bf2f(unsigned short u){ union{unsigned int i; float f;} v; v.i=((unsigned int)u)<<16; return v.f; }
DEV unsigned short f2bf(float f){ union{float f; unsigned int i;} v; v.f=f; unsigned int x=v.i;
  return (unsigned short)((x + 0x7fffu + ((x>>16)&1u)) >> 16); }

// ---------------------------------------------------------------------------
// Fused s=1 prep: theta = (W_t x + b_t)*10*log2(e)  [bf16 CL padded 134x136x16]
//                 phi0  = W_p x + b_p               [bf16 CL padded]
//                 g0    = W_g x + b_g               [f32 CF padded 16x134x136]
// ---------------------------------------------------------------------------
__global__ void k_prep1(const float* __restrict__ x,
                        const float* __restrict__ wt, const float* __restrict__ bt,
                        const float* __restrict__ wp, const float* __restrict__ bp,
                        const float* __restrict__ wg, const float* __restrict__ bg,
                        unsigned short* __restrict__ th, unsigned short* __restrict__ ph,
                        float* __restrict__ gt)
{
  __shared__ float red[3][64][48];
  int tid = threadIdx.x;
  int grp = tid >> 6, pixl = tid & 63;
  int pix = blockIdx.x*64 + pixl;          // [0, 32768)
  int b = pix >> 14, p = pix & 16383, i = p >> 7, j = p & 127;
  float a[48];
#pragma unroll
  for (int c=0;c<48;++c) a[c]=0.f;
  const float* xb = x + (size_t)b*64*16384 + p;
#pragma unroll
  for (int c4=0; c4<4; ++c4) {
    int cc = grp*16 + c4*4;
    float xv[4];
#pragma unroll
    for (int u=0;u<4;++u) xv[u] = xb[(size_t)(cc+u)*16384];
#pragma unroll
    for (int ic=0;ic<16;++ic) {
      float4 w0 = *(const float4*)(wt + ic*64 + cc);
      float4 w1 = *(const float4*)(wp + ic*64 + cc);
      float4 w2 = *(const float4*)(wg + ic*64 + cc);
      a[ic]    += xv[0]*w0.x + xv[1]*w0.y + xv[2]*w0.z + xv[3]*w0.w;
      a[16+ic] += xv[0]*w1.x + xv[1]*w1.y + xv[2]*w1.z + xv[3]*w1.w;
      a[32+ic] += xv[0]*w2.x + xv[1]*w2.y + xv[2]*w2.z + xv[3]*w2.w;
    }
  }
  if (grp) {
#pragma unroll
    for (int c=0;c<48;++c) red[grp-1][pixl][c] = a[c];
  }
  __syncthreads();
  if (grp == 0) {
#pragma unroll
    for (int c=0;c<48;++c) a[c] += red[0][pixl][c] + red[1][pixl][c] + red[2][pixl][c];
    const float TEMPC = 14.426950408889634f;
    unsigned short o[16];
#pragma unroll
    for (int ic=0;ic<16;++ic) o[ic] = f2bf((a[ic]+bt[ic])*TEMPC);
    uint4* d0 = (uint4*)(th + ((size_t)(b*134 + i+3)*136 + (j+3))*16);
    d0[0]=*(uint4*)&o[0]; d0[1]=*(uint4*)&o[8];
#pragma unroll
    for (int ic=0;ic<16;++ic) o[ic] = f2bf(a[16+ic]+bp[ic]);
    uint4* d1 = (uint4*)(ph + ((size_t)(b*134 + i+3)*136 + (j+3))*16);
    d1[0]=*(uint4*)&o[0]; d1[1]=*(uint4*)&o[8];
#pragma unroll
    for (int ic=0;ic<16;++ic)
      gt[(((size_t)b*16+ic)*134 + i+3)*136 + (j+3)] = a[32+ic]+bg[ic];
  }
}

// ---------------------------------------------------------------------------
// s=2 conv: phi1 (bf16 CL padded 70x72x16), g1 (f32 CF padded 16x70x72)
// ---------------------------------------------------------------------------
__global__ void k_conv2(const float* __restrict__ x,
                        const float* __restrict__ wp, const float* __restrict__ bp,
                        const float* __restrict__ wg, const float* __restrict__ bg,
                        unsigned short* __restrict__ phi, float* __restrict__ gt)
{
  __shared__ float red[3][64][32];
  int tid = threadIdx.x;
  int grp = tid >> 6, pixl = tid & 63;
  int pix = blockIdx.x*64 + pixl;          // [0, 8192)
  int b = pix >> 12, p = pix & 4095, i = p >> 6, j = p & 63;
  float a[32];
#pragma unroll
  for (int c=0;c<32;++c) a[c]=0.f;
  const float* xb = x + (size_t)b*64*16384 + (i*2)*128 + j*2;
#pragma unroll
  for (int c0=0; c0<16; ++c0) {
    int cc = grp*16 + c0;
    const float* xp = xb + (size_t)cc*16384;
    float xv[4];
    xv[0]=xp[0]; xv[1]=xp[1]; xv[2]=xp[128]; xv[3]=xp[129];
#pragma unroll
    for (int ic=0;ic<16;++ic) {
      float4 w0 = *(const float4*)(wp + (ic*64+cc)*4);
      float4 w1 = *(const float4*)(wg + (ic*64+cc)*4);
      a[ic]    += xv[0]*w0.x + xv[1]*w0.y + xv[2]*w0.z + xv[3]*w0.w;
      a[16+ic] += xv[0]*w1.x + xv[1]*w1.y + xv[2]*w1.z + xv[3]*w1.w;
    }
  }
  if (grp) {
#pragma unroll
    for (int c=0;c<32;++c) red[grp-1][pixl][c] = a[c];
  }
  __syncthreads();
  if (grp == 0) {
#pragma unroll
    for (int c=0;c<32;++c) a[c] += red[0][pixl][c] + red[1][pixl][c] + red[2][pixl][c];
    unsigned short o[16];
#pragma unroll
    for (int ic=0;ic<16;++ic) o[ic] = f2bf(a[ic]+bp[ic]);
    uint4* d1 = (uint4*)(phi + ((size_t)(b*70 + i+3)*72 + (j+3))*16);
    d1[0]=*(uint4*)&o[0]; d1[1]=*(uint4*)&o[8];
#pragma unroll
    for (int ic=0;ic<16;++ic)
      gt[(((size_t)b*16+ic)*70 + i+3)*72 + (j+3)] = a[16+ic]+bg[ic];
  }
}

// ---------------------------------------------------------------------------
// Transpose s=4 weights: wT[k][32], k = cc*16 + a*4 + bb; c<16 phi, else g
// ---------------------------------------------------------------------------
__global__ void k_wt4(const float* __restrict__ wp, const float* __restrict__ wg,
                      float* __restrict__ wT)
{
  int idx = blockIdx.x*256 + threadIdx.x;
  if (idx >= 1024*32) return;
  int k = idx >> 5, c = idx & 31;
  int cc = k >> 4, ksp = k & 15;
  float v = (c < 16) ? wp[(c*64+cc)*16 + ksp] : wg[((c-16)*64+cc)*16 + ksp];
  wT[idx] = v;
}

// ---------------------------------------------------------------------------
// s=4 conv: 8 pixels x 32 out-channels; x patches staged in LDS
// ---------------------------------------------------------------------------
__global__ void k_conv4(const float* __restrict__ x, const float* __restrict__ wT,
                        const float* __restrict__ bp, const float* __restrict__ bg,
                        unsigned short* __restrict__ phi, float* __restrict__ gt)
{
  __shared__ float xs[8][1028];
  int tid = threadIdx.x;
  int pix0 = blockIdx.x*8;                 // [0,2048) step 8
  for (int idx = tid; idx < 8*1024; idx += 256) {
    int pl = idx >> 10, e = idx & 1023;
    int pix = pix0 + pl; int b = pix >> 10, p = pix & 1023, i = p >> 5, j = p & 31;
    int cc = e >> 4, a_ = (e >> 2) & 3, bb = e & 3;
    xs[pl][e] = x[(((size_t)b*64+cc)*128 + i*4+a_)*128 + j*4+bb];
  }
  __syncthreads();
  int pp = tid >> 5, icp = tid & 31;
  int pix = pix0 + pp; int b = pix >> 10, p = pix & 1023, i = p >> 5, j = p & 31;
  float acc = 0.f;
#pragma unroll 8
  for (int k4=0; k4<256; ++k4) {
    float4 xv = *(const float4*)(&xs[pp][k4*4]);
    acc += xv.x*wT[(k4*4  )*32+icp] + xv.y*wT[(k4*4+1)*32+icp]
         + xv.z*wT[(k4*4+2)*32+icp] + xv.w*wT[(k4*4+3)*32+icp];
  }
  int ic = icp & 15;
  if (icp < 16)
    phi[(((size_t)(b*38 + i+3)*40) + (j+3))*16 + ic] = f2bf(acc + bp[ic]);
  else
    gt[(((size_t)b*16+ic)*38 + i+3)*40 + (j+3)] = acc + bg[ic];
}

// ---------------------------------------------------------------------------
// V tile buffer: g8b[b][sh][y][xb][c][32] bf16 (1KB tile per (sh,y,xb)).
// ---------------------------------------------------------------------------
template<int HP, int WX, int HS>
__global__ void k_shiftB(const float* __restrict__ gt, unsigned short* __restrict__ g8b)
{
  const int XB = HS/32;
  int idx = blockIdx.x*256 + threadIdx.x;
  const int TOT = 2*8*HP*XB*16*4;
  if (idx >= TOT) return;
  int xkg = idx & 3;
  int c = (idx >> 2) & 15;
  int t = idx >> 6;
  int xb = t % XB; t /= XB;
  int y = t % HP; t /= HP;
  int sh = t & 7; int b = t >> 3;
  const float* src = gt + (((size_t)b*16+c)*HP + y)*WX + xb*32 + xkg*8 + sh;
  unsigned short o[8];
#pragma unroll
  for (int j=0;j<8;++j) o[j] = f2bf(src[j]);
  unsigned short* dst = g8b + ((((size_t)(b*8+sh)*HP + y)*XB + xb)*16 + c)*32 + xkg*8;
  *(uint4*)dst = *(uint4*)&o[0];
}

// ---------------------------------------------------------------------------
// Flash attention body (round-11 structure): fixed shift P=exp2(min(sc-64,120)),
// Q-tile 32, 8 waves, 256 keys/iter. theta staged once into swizzled LDS;
// phi from global (coalesced, streaming); V nontemporal from g8b tiles;
// accP nontemporal. slot0 offsets the accP/lP chunk slots (for merged grid).
// ---------------------------------------------------------------------------
template<int HS, int LG, int HP, int WX, int CK, int NCH>
DEV void attn_body(int bid, int slot0,
                   const unsigned short* __restrict__ th,
                   const unsigned short* __restrict__ phi,
                   const unsigned short* __restrict__ g8b,
                   float* __restrict__ accP, float* __restrict__ lP, char* smem)
{
  const int PO = 30464;
  int tid = threadIdx.x;
  int w = tid >> 6, lane = tid & 63, l15 = lane & 15, g = lane >> 4;
  int chunk, b, qt;
  if (NCH == 8) { chunk = bid & 7; b = (bid >> 3) & 1; qt = bid >> 4; }
  else          { chunk = bid & 3; b = (bid >> 2) & 1; qt = bid >> 3; }
  int q0 = qt * 32;
  int slot = slot0 + chunk;

  const char* thB  = (const char*)th  + (size_t)b*134*136*32;
  const char* phiB = (const char*)phi + (size_t)b*HP*WX*32;

  // ---- stage theta window (rows 4qt+2 .. 4qt+8) into swizzled LDS ----
  for (int u = tid; u < 7*136*2; u += 512) {
    int half = u & 1; int cu = (u >> 1) % 136; int r = (u >> 1) / 136;
    uint4 v = *(const uint4*)(thB + (((4*qt+2+r)*136 + cu)*32 + half*16));
    int la = (((r*136 + cu)*32) + half*16) ^ (((cu >> 2) & 7) << 4);
    *(uint4*)(smem + la) = v;
  }
  __syncthreads();

  f32x4 acc[2][7];
#pragma unroll
  for (int rt=0;rt<2;++rt)
#pragma unroll
    for (int et=0;et<7;++et) acc[rt][et] = f32x4{0.f,0.f,0.f,0.f};
  float lacc[2][4];
#pragma unroll
  for (int rt=0;rt<2;++rt)
#pragma unroll
    for (int r=0;r<4;++r) lacc[rt][r] = 0.f;

  const int XBv = HS/32;
  const char* g8B  = (const char*)g8b + (size_t)b*8*HP*XBv*1024;
  const int EPL = HP*XBv*1024;                 // bytes per shift-plane
  int laneVb = l15*64 + g*16;                  // within 1KB tile
  int xrP = (l15 & 7) << 4;                    // P-lds read swizzle
  int colb = 4*l15 + 2;                        // theta col base (a0); a1 = +64
  int hb = (g & 1) << 4;
  const bf16x8 ZV = {0,0,0,0,0,0,0,0};
  const int ITERS = CK/256;
  const float SHIFT = 64.0f, CLAMP = 120.0f;

#pragma unroll 1
  for (int it = 0; it < ITERS; ++it) {
    int k0 = chunk*CK + it*256;
    // ---------------- QK ----------------
    f32x4 sc[2][2];
#pragma unroll
    for (int rt=0;rt<2;++rt){ sc[rt][0]=f32x4{0.f,0.f,0.f,0.f}; sc[rt][1]=f32x4{0.f,0.f,0.f,0.f}; }
    int kr_w = (k0 + w*32) >> LG;
    int kc_w = (w*32) & (HS-1);
    int base0 = (kr_w*WX + kc_w + l15)*32 + hb;
    int base1 = base0 + 512;
#pragma unroll
    for (int ks=0; ks<25; ++ks) {
      int p0 = 2*ks;
      int p1 = (2*ks+1 > 48) ? 48 : 2*ks+1;
      int dr0 = p0/7, dc0 = p0%7;
      int dr1 = p1/7, dc1 = p1%7;
      int c0 = colb + dc0, c1 = colb + dc1;
      int la0 = ((dr0*136 + c0)*32 + hb) ^ (((c0 >> 2) & 7) << 4);
      int la1 = ((dr1*136 + c1)*32 + hb) ^ (((c1 >> 2) & 7) << 4);
      int laA = (g & 2) ? la1 : la0;
      int KB0 = (dr0*WX + dc0)*32;
      int KB1 = (dr1*WX + dc1)*32;
      int selB = (g & 2) ? KB1 : KB0;
      bf16x8 a0 = *(const bf16x8*)(smem + laA);
      bf16x8 a1 = *(const bf16x8*)(smem + laA + 2048);   // +64 cols, same swizzle
      if (ks == 24) {
        bool z = (g & 2) != 0;
        a0 = z ? ZV : a0; a1 = z ? ZV : a1;
      }
      bf16x8 b0 = *(const bf16x8*)(phiB + base0 + selB);
      bf16x8 b1 = *(const bf16x8*)(phiB + base1 + selB);
      sc[0][0] = __builtin_amdgcn_mfma_f32_16x16x32_bf16(a0, b0, sc[0][0], 0,0,0);
      sc[0][1] = __builtin_amdgcn_mfma_f32_16x16x32_bf16(a0, b1, sc[0][1], 0,0,0);
      sc[1][0] = __builtin_amdgcn_mfma_f32_16x16x32_bf16(a1, b0, sc[1][0], 0,0,0);
      sc[1][1] = __builtin_amdgcn_mfma_f32_16x16x32_bf16(a1, b1, sc[1][1], 0,0,0);
    }
    // ---------------- P = exp2(min(S-64,120)), accumulate l, write P_lds ----------------
#pragma unroll
    for (int rt=0;rt<2;++rt) {
#pragma unroll
      for (int r=0;r<4;++r) {
        float pa = __builtin_amdgcn_exp2f(fminf(sc[rt][0][r] - SHIFT, CLAMP));
        float pb = __builtin_amdgcn_exp2f(fminf(sc[rt][1][r] - SHIFT, CLAMP));
        lacc[rt][r] += pa + pb;
        int q_ = rt*16 + g*4 + r;
        int offa = q_*512 + (w*32 + l15)*2;      offa ^= (q_&7)<<4;
        int offb = q_*512 + (w*32 + 16 + l15)*2; offb ^= (q_&7)<<4;
        *(unsigned short*)(smem + PO + offa) = f2bf(pa);
        *(unsigned short*)(smem + PO + offb) = f2bf(pb);
      }
    }
    __syncthreads();                               // B1: P ready
    // ---------------- PV ----------------
    if (w < 7) {
#pragma unroll
      for (int ks2=0; ks2<8; ++ks2) {
        int kk = k0 + ks2*32;
        int krv = kk >> LG;
        int kcb = kk & (HS-1);
        bf16x8 pf[2];
#pragma unroll
        for (int rt=0;rt<2;++rt) {
          int off = (rt*16 + l15)*512 + ks2*64 + g*16;
          off ^= xrP;
          pf[rt] = *(const bf16x8*)(smem + PO + off);
        }
        int vb = ((krv + w)*XBv + (kcb >> 5))*1024 + laneVb;
        bf16x8 vf[7];
#pragma unroll
        for (int et=0;et<7;++et) {
          u32x4 t0 = __builtin_nontemporal_load((const u32x4*)(g8B + vb + et*EPL));
          vf[et] = *(bf16x8*)&t0;
        }
        __builtin_amdgcn_s_setprio(1);
#pragma unroll
        for (int rt=0;rt<2;++rt)
#pragma unroll
          for (int et=0;et<7;++et)
            acc[rt][et] = __builtin_amdgcn_mfma_f32_16x16x32_bf16(pf[rt], vf[et], acc[rt][et], 0,0,0);
        __builtin_amdgcn_s_setprio(0);
      }
    }
    __syncthreads();                               // B2: protect P
  }
  if (w < 7) {
    float* accB = accP + ((size_t)(slot*2 + b)*1024)*784;
#pragma unroll
    for (int rt=0;rt<2;++rt)
#pragma unroll
      for (int et=0;et<7;++et)
#pragma unroll
        for (int r=0;r<4;++r)
          __builtin_nontemporal_store(acc[rt][et][r],
            &accB[(size_t)(q0 + rt*16 + g*4 + r)*784 + (w*7+et)*16 + l15]);
  }
#pragma unroll
  for (int st=1; st<16; st<<=1)
#pragma unroll
    for (int rt=0;rt<2;++rt)
#pragma unroll
      for (int r=0;r<4;++r) lacc[rt][r] += __shfl_xor(lacc[rt][r], st);
  if (l15 == 0) {
#pragma unroll
    for (int rt=0;rt<2;++rt)
#pragma unroll
      for (int r=0;r<4;++r)
        lP[((size_t)((slot*2 + b)*8 + w) << 10) + q0 + rt*16 + g*4 + r] = lacc[rt][r];
  }
}

template<int HS, int LG, int HP, int WX, int CK, int NCH>
__global__ void __launch_bounds__(512, 2)
k_attn(const unsigned short* __restrict__ th, const unsigned short* __restrict__ phi,
       const unsigned short* __restrict__ g8b, float* __restrict__ accP,
       float* __restrict__ lP)
{
  __shared__ __align__(16) char smem[30464 + 16384];
  attn_body<HS,LG,HP,WX,CK,NCH>(blockIdx.x, 0, th, phi, g8b, accP, lP, smem);
}

__global__ void __launch_bounds__(512, 2)
k_attn_all(const unsigned short* __restrict__ th,
           const unsigned short* __restrict__ ph0, const unsigned short* __restrict__ ph1,
           const unsigned short* __restrict__ ph2,
           const unsigned short* __restrict__ g80, const unsigned short* __restrict__ g81,
           const unsigned short* __restrict__ g82,
           float* __restrict__ accP, float* __restrict__ lP)
{
  __shared__ __align__(16) char smem[30464 + 16384];
  int bid = blockIdx.x;
  if (bid < 512)       attn_body<128,7,134,136,2048,8>(bid,      0,  th, ph0, g80, accP, lP, smem);
  else if (bid < 1024) attn_body<64,6,70,72,512,8>   (bid-512,  8,  th, ph1, g81, accP, lP, smem);
  else                 attn_body<32,5,38,40,256,4>   (bid-1024, 16, th, ph2, g82, accP, lP, smem);
}

// ---------------------------------------------------------------------------
// lG[b*1024+q] = sum over chunks and waves of lP
// ---------------------------------------------------------------------------
__global__ void k_comb1(const float* __restrict__ lP, float* __restrict__ lG, int nch)
{
  int idx = blockIdx.x*256 + threadIdx.x;
  if (idx >= 2048) return;
  int b = idx >> 10, q = idx & 1023;
  float l = 0.f;
  for (int c=0;c<nch;++c)
#pragma unroll
    for (int w=0;w<8;++w)
      l += lP[((size_t)((c*2 + b)*8 + w) << 10) + q];
  lG[idx] = l;
}

// ---------------------------------------------------------------------------
// Sum partial accs over chunks (directly summable, shared shift), / lG
// ---------------------------------------------------------------------------
__global__ void k_comb2(const float* __restrict__ accP, const float* __restrict__ lG,
                        float* __restrict__ yvf, int nch)
{
  int idx = blockIdx.x*256 + threadIdx.x;
  if (idx >= 2048*196) return;
  int bq = idx / 196, f4 = idx % 196;
  float4 s = {0.f,0.f,0.f,0.f};
  for (int c=0;c<nch;++c) {
    float4 v = *(const float4*)(accP + ((size_t)(c*2048 + bq))*784 + f4*4);
    s.x += v.x; s.y += v.y; s.z += v.z; s.w += v.w;
  }
  float inv = 1.0f / lG[bq];
  s.x*=inv; s.y*=inv; s.z*=inv; s.w*=inv;
  *(float4*)(yvf + (size_t)bq*784 + f4*4) = s;
}

// ---------------------------------------------------------------------------
// fold (stride-4, pad 3) + /mask -> y_cl[b][i][j][48]
// ---------------------------------------------------------------------------
template<int SC>
__global__ void k_fold_f32(const float* __restrict__ yvf, float* __restrict__ ycl)
{
  int idx = blockIdx.x*256 + threadIdx.x;
  if (idx >= 2*128*128) return;
  int j = idx & 127; int t = idx >> 7; int i = t & 127; int b = t >> 7;
  float a[16];
#pragma unroll
  for (int c=0;c<16;++c) a[c]=0.f;
  const float* yb = yvf + (size_t)b*1024*784;

  int drs[2], qis[2], cnti=0;
  int dcs[2], qjs[2], cntj=0;
#pragma unroll
  for (int dr=0; dr<7; ++dr) {
    int tr = i + 3 - dr;
    if (tr >= 0 && (tr & 3) == 0 && (tr >> 2) < 32) { drs[cnti]=dr; qis[cnti]=tr>>2; ++cnti; }
  }
#pragma unroll
  for (int dc=0; dc<7; ++dc) {
    int tc = j + 3 - dc;
    if (tc >= 0 && (tc & 3) == 0 && (tc >> 2) < 32) { dcs[cntj]=dc; qjs[cntj]=tc>>2; ++cntj; }
  }
  for (int u=0; u<cnti; ++u) {
    for (int v=0; v<cntj; ++v) {
      const float* src = yb + (size_t)(qis[u]*32 + qjs[v])*784 + (drs[u]*7 + dcs[v])*16;
      float4 v0 = *(const float4*)(src);
      float4 v1 = *(const float4*)(src+4);
      float4 v2 = *(const float4*)(src+8);
      float4 v3 = *(const float4*)(src+12);
      a[0]+=v0.x; a[1]+=v0.y; a[2]+=v0.z; a[3]+=v0.w;
      a[4]+=v1.x; a[5]+=v1.y; a[6]+=v1.z; a[7]+=v1.w;
      a[8]+=v2.x; a[9]+=v2.y; a[10]+=v2.z; a[11]+=v2.w;
      a[12]+=v3.x; a[13]+=v3.y; a[14]+=v3.z; a[15]+=v3.w;
    }
  }
  float inv = 1.0f / (float)(cnti*cntj);
  float* dst = ycl + (size_t)idx*48 + SC*16;
#pragma unroll
  for (int c=0;c<16;++c) dst[c] = a[c]*inv;
}

// ---------------------------------------------------------------------------
// out = conv1x1(y, w_out) + b_out + x
// ---------------------------------------------------------------------------
__global__ void k_final(const float* __restrict__ ycl, const float* __restrict__ wo,
                        const float* __restrict__ bo, const float* __restrict__ x,
                        float* __restrict__ out)
{
  __shared__ float wl[64*48];
  for (int t = threadIdx.x; t < 64*48; t += 256) wl[t] = wo[t];
  __syncthreads();
  int idx = blockIdx.x*256 + threadIdx.x;
  if (idx >= 2*128*128) return;
  int j = idx & 127; int t = idx >> 7; int i = t & 127; int b = t >> 7;
  float y[48];
  const float* ys = ycl + (size_t)idx*48;
#pragma unroll
  for (int c=0;c<48;++c) y[c] = ys[c];
  const float* xb = x + (size_t)b*64*16384 + i*128 + j;
  float* ob = out + (size_t)b*64*16384 + i*128 + j;
  for (int o=0;o<64;++o) {
    float s = bo[o];
#pragma unroll
    for (int c=0;c<48;++c) s += y[c]*wl[o*48+c];
    ob[(size_t)o*16384] = s + xb[(size_t)o*16384];
  }
}

// ---------------------------------------------------------------------------
extern "C" void kernel_launch(void* const* d_in, const int* in_sizes, int n_in,
                              void* d_out, int out_size, void* d_ws, size_t ws_size,
                              hipStream_t stream)
{
  const float* x  = (const float*)d_in[0];
  const float* wt = (const float*)d_in[1];
  const float* bt = (const float*)d_in[2];
  const float* wp0= (const float*)d_in[3];
  const float* bp0= (const float*)d_in[4];
  const float* wg0= (const float*)d_in[5];
  const float* bg0= (const float*)d_in[6];
  const float* wp1= (const float*)d_in[7];
  const float* bp1= (const float*)d_in[8];
  const float* wg1= (const float*)d_in[9];
  const float* bg1= (const float*)d_in[10];
  const float* wp2= (const float*)d_in[11];
  const float* bp2= (const float*)d_in[12];
  const float* wg2= (const float*)d_in[13];
  const float* bg2= (const float*)d_in[14];
  const float* wo = (const float*)d_in[15];
  const float* bo = (const float*)d_in[16];
  float* out = (float*)d_out;
  (void)in_sizes; (void)n_in; (void)out_size;

  char* ws = (char*)d_ws;
  unsigned short *th, *ph0, *ph1, *ph2, *g80, *g81, *g82;
  float *gt0, *gt1, *gt2, *wT4, *lP, *lG, *accP, *yvf, *ycl;
  size_t zeroBytes = 0, total = 0;

  auto layout = [&](int slots)->size_t {
    size_t off = 0;
    auto alloc = [&](size_t bytes)->char* { char* p = ws + off; off += (bytes + 255) & ~(size_t)255; return p; };
    th  = (unsigned short*)alloc(2ull*134*136*16*2);
    ph0 = (unsigned short*)alloc(2ull*134*136*16*2);
    ph1 = (unsigned short*)alloc(2ull*70*72*16*2);
    ph2 = (unsigned short*)alloc(2ull*38*40*16*2);
    gt0 = (float*)alloc(2ull*16*134*136*4);
    gt1 = (float*)alloc(2ull*16*70*72*4);
    gt2 = (float*)alloc(2ull*16*38*40*4);
    zeroBytes = off;                         // th..gt2 contiguous prefix
    g80 = (unsigned short*)alloc(2ull*8*134*4*512*2);
    g81 = (unsigned short*)alloc(2ull*8*70*2*512*2);
    g82 = (unsigned short*)alloc(2ull*8*38*1*512*2);
    wT4 = (float*)alloc(1024ull*32*4);
    lP  = (float*)alloc((size_t)slots*2*8*1024*4);
    lG  = (float*)alloc(2048*4);
    accP= (float*)alloc((size_t)slots*2048*784*4);
    yvf = (float*)alloc(2048ull*784*4);
    ycl = (float*)alloc(2ull*128*128*48*4);
    return off;
  };

  total = layout(20);
  bool merged = (total <= ws_size);
  if (!merged) total = layout(8);

  (void)hipMemsetAsync(ws, 0, zeroBytes, stream);  // zero padded borders of th/ph/gt

  k_prep1<<<512,256,0,stream>>>(x, wt,bt, wp0,bp0, wg0,bg0, th, ph0, gt0);
  k_conv2<<<128,256,0,stream>>>(x, wp1,bp1, wg1,bg1, ph1, gt1);
  k_wt4<<<128,256,0,stream>>>(wp2, wg2, wT4);
  k_conv4<<<256,256,0,stream>>>(x, wT4, bp2, bg2, ph2, gt2);
  k_shiftB<134,136,128><<<(2*8*134*4*16*4+255)/256,256,0,stream>>>(gt0, g80);
  k_shiftB<70,72,64>   <<<(2*8*70*2*16*4 +255)/256,256,0,stream>>>(gt1, g81);
  k_shiftB<38,40,32>   <<<(2*8*38*1*16*4 +255)/256,256,0,stream>>>(gt2, g82);

  const int CB2 = (2048*196 + 255)/256;
  if (merged) {
    k_attn_all<<<1280,512,0,stream>>>(th, ph0,ph1,ph2, g80,g81,g82, accP, lP);
    // scale 0: slots 0-7
    k_comb1<<<8,256,0,stream>>>(lP, lG, 8);
    k_comb2<<<CB2,256,0,stream>>>(accP, lG, yvf, 8);
    k_fold_f32<0><<<128,256,0,stream>>>(yvf, ycl);
    // scale 1: slots 8-15
    k_comb1<<<8,256,0,stream>>>(lP + 8ull*2*8*1024, lG, 8);
    k_comb2<<<CB2,256,0,stream>>>(accP + 8ull*2048*784, lG, yvf, 8);
    k_fold_f32<1><<<128,256,0,stream>>>(yvf, ycl);
    // scale 2: slots 16-19
    k_comb1<<<8,256,0,stream>>>(lP + 16ull*2*8*1024, lG, 4);
    k_comb2<<<CB2,256,0,stream>>>(accP + 16ull*2048*784, lG, yvf, 4);
    k_fold_f32<2><<<128,256,0,stream>>>(yvf, ycl);
  } else {
    k_attn<128,7,134,136,2048,8><<<512,512,0,stream>>>(th, ph0, g80, accP, lP);
    k_comb1<<<8,256,0,stream>>>(lP, lG, 8);
    k_comb2<<<CB2,256,0,stream>>>(accP, lG, yvf, 8);
    k_fold_f32<0><<<128,256,0,stream>>>(yvf, ycl);
    k_attn<64,6,70,72,512,8><<<512,512,0,stream>>>(th, ph1, g81, accP, lP);
    k_comb1<<<8,256,0,stream>>>(lP, lG, 8);
    k_comb2<<<CB2,256,0,stream>>>(accP, lG, yvf, 8);
    k_fold_f32<1><<<128,256,0,stream>>>(yvf, ycl);
    k_attn<32,5,38,40,256,4><<<256,512,0,stream>>>(th, ph2, g82, accP, lP);
    k_comb1<<<8,256,0,stream>>>(lP, lG, 4);
    k_comb2<<<CB2,256,0,stream>>>(accP, lG, yvf, 4);
    k_fold_f32<2><<<128,256,0,stream>>>(yvf, ycl);
  }

  k_final<<<128,256,0,stream>>>(ycl, wo, bo, x, out);
}